// Round 1
// baseline (24.126 us; speedup 1.0000x reference)
//
#include <hip/hip_runtime.h>
#include <math.h>

// Quanvolution: 8192 images of 28x28, 14x14 grid of 2x2 patches, each patch
// drives a 4-qubit real-amplitude circuit (RY encoding + 2 layers of RY+CNOT
// ring), output <Z_w> per wire -> (8192, 784) float32.
//
// One thread per patch. 16-amplitude state lives entirely in registers with
// compile-time indexing (full unroll). Wire w corresponds to bit weight
// (8 >> w) of the flattened state index (q0 = MSB).

#define N_TOTAL (8192 * 196)

__global__ __launch_bounds__(256) void quanv_kernel(
    const float* __restrict__ x,       // (8192, 28, 28)
    const float* __restrict__ params,  // (2, 4)
    float* __restrict__ out)           // (8192, 784)
{
    int idx = blockIdx.x * blockDim.x + threadIdx.x;
    if (idx >= N_TOTAL) return;

    int b = idx / 196;
    int p = idx - b * 196;
    int r = p / 14;
    int c = p - r * 14;

    // 2x2 patch: pixels (2r,2c),(2r,2c+1),(2r+1,2c),(2r+1,2c+1)
    const float* px = x + b * 784 + (2 * r) * 28 + 2 * c;
    float2 row0 = *reinterpret_cast<const float2*>(px);
    float2 row1 = *reinterpret_cast<const float2*>(px + 28);
    float ang0 = row0.x, ang1 = row0.y, ang2 = row1.x, ang3 = row1.y;

    // Angle encoding: product state  ⊗_w [cos(a_w/2), sin(a_w/2)]
    float cw[4], sw[4];
    __sincosf(ang0 * 0.5f, &sw[0], &cw[0]);
    __sincosf(ang1 * 0.5f, &sw[1], &cw[1]);
    __sincosf(ang2 * 0.5f, &sw[2], &cw[2]);
    __sincosf(ang3 * 0.5f, &sw[3], &cw[3]);

    float a[16];
#pragma unroll
    for (int i = 0; i < 16; ++i) {
        float v = ((i & 8) ? sw[0] : cw[0]);
        v *= ((i & 4) ? sw[1] : cw[1]);
        v *= ((i & 2) ? sw[2] : cw[2]);
        v *= ((i & 1) ? sw[3] : cw[3]);
        a[i] = v;
    }

    // Variational layers: RY(params[l][w]) on each wire, then CNOT ring.
#pragma unroll
    for (int l = 0; l < 2; ++l) {
        // RY gates (params are wave-uniform -> scalar loads)
#pragma unroll
        for (int w = 0; w < 4; ++w) {
            float th = params[l * 4 + w] * 0.5f;
            float ps, pc;
            __sincosf(th, &ps, &pc);
            const int stride = 8 >> w;
#pragma unroll
            for (int i = 0; i < 16; ++i) {
                if (i & stride) continue;
                float s0 = a[i];
                float s1 = a[i + stride];
                a[i]          = pc * s0 - ps * s1;
                a[i + stride] = ps * s0 + pc * s1;
            }
        }
        // CNOT(w, (w+1)%4): within ctrl=1 subspace, swap target bit.
#pragma unroll
        for (int w = 0; w < 4; ++w) {
            const int cstride = 8 >> w;
            const int tstride = 8 >> ((w + 1) & 3);
#pragma unroll
            for (int i = 0; i < 16; ++i) {
                if (!(i & cstride)) continue;
                if (i & tstride) continue;
                float t = a[i];
                a[i] = a[i | tstride];
                a[i | tstride] = t;
            }
        }
    }

    // <Z_w> = sum_i (+-) a_i^2, sign by bit w of i.
    float z0 = 0.f, z1 = 0.f, z2 = 0.f, z3 = 0.f;
#pragma unroll
    for (int i = 0; i < 16; ++i) {
        float p2 = a[i] * a[i];
        z0 += (i & 8) ? -p2 : p2;
        z1 += (i & 4) ? -p2 : p2;
        z2 += (i & 2) ? -p2 : p2;
        z3 += (i & 1) ? -p2 : p2;
    }

    *reinterpret_cast<float4*>(out + (size_t)idx * 4) = make_float4(z0, z1, z2, z3);
}

extern "C" void kernel_launch(void* const* d_in, const int* in_sizes, int n_in,
                              void* d_out, int out_size, void* d_ws, size_t ws_size,
                              hipStream_t stream) {
    const float* x      = (const float*)d_in[0];  // (8192,28,28) f32
    const float* params = (const float*)d_in[1];  // (2,4) f32
    float* out          = (float*)d_out;          // (8192,784) f32

    const int total = N_TOTAL;
    const int block = 256;
    const int grid  = (total + block - 1) / block;
    quanv_kernel<<<grid, block, 0, stream>>>(x, params, out);
}